// Round 16
// baseline (422.813 us; speedup 1.0000x reference)
//
#include <hip/hip_runtime.h>
#include <hip/hip_bf16.h>

// ---------------------------------------------------------------------------
// ROUND 16: bit-packed mask. R13/R14/R15 triangulation: scattered 128B-line
// mask reads plateau at 1-2 TB/s regardless of occupancy => shrink demand
// 32x instead of tuning the pattern. k_pack (one wave per row, sequential
// 256B/instr reads, __ballot) builds packed[rowblk=500][t=250][m=16] uint32
// (8 MB); k_attn reads 16 contiguous words (64 B) per iteration — L2/L3
// resident. New attn floor = WhB frag L2 traffic (~30us) + exp2 compute.
// Everything else identical to R15 (merged-head MFMA, njy j-split).
// ---------------------------------------------------------------------------

#define CN1 3000
#define CN2 2500
#define CN3 2500
#define NTOT 8000
#define INF_ 128
#define OUTF 64
#define LOG2E 1.44269504088896340736f
#define ALPHA 0.2f

typedef __attribute__((ext_vector_type(4))) float f32x4;
typedef __attribute__((ext_vector_type(8))) short short8;
union B16x8 { int4 i4; short8 s8; unsigned int u[4]; };

#if defined(__has_builtin)
#if __has_builtin(__builtin_amdgcn_exp2f)
#define EXP2F(x) __builtin_amdgcn_exp2f(x)
#endif
#endif
#ifndef EXP2F
#define EXP2F(x) exp2f(x)
#endif

__device__ inline float wave_sum(float v) {
  for (int d = 32; d; d >>= 1) v += __shfl_xor(v, d, 64);
  return v;
}

__device__ inline unsigned int pack2_bf16(float a, float b) {
  unsigned ua = __float_as_uint(a);
  ua = (ua + 0x7FFFu + ((ua >> 16) & 1u)) >> 16;
  unsigned ub = __float_as_uint(b);
  ub = (ub + 0x7FFFu + ((ub >> 16) & 1u)) & 0xFFFF0000u;
  return ub | ua;
}

// ---------------- k_pack: mask -> bits, fragment-friendly layout ------------
// wave = one row i. Reads 64 ints/iter (256 B contiguous per band), ballots,
// writes packed[i>>4][t][i&15], t = j/32. 8000 waves, fully streaming.
__global__ __launch_bounds__(256)
void k_pack(const int* __restrict__ A1,  const int* __restrict__ A12, const int* __restrict__ A13,
            const int* __restrict__ A21, const int* __restrict__ A2,  const int* __restrict__ A23,
            const int* __restrict__ A31, const int* __restrict__ A32, const int* __restrict__ A3,
            unsigned int* __restrict__ packed) {
  const int i = blockIdx.x * 4 + (threadIdx.x >> 6);
  const int lane = threadIdx.x & 63;
  const int *p0, *p1, *p2;
  if (i < CN1)            { p0 = A1  + i * CN1;          p1 = A12 + i * CN2;          p2 = A13 + i * CN3; }
  else if (i < CN1 + CN2) { int r = i - CN1;       p0 = A21 + r * CN1; p1 = A2  + r * CN2; p2 = A23 + r * CN3; }
  else                    { int r = i - CN1 - CN2; p0 = A31 + r * CN1; p1 = A32 + r * CN2; p2 = A3  + r * CN3; }
  unsigned int* pkrow = packed + (i >> 4) * 4000 + (i & 15);
  for (int c = 0; c < 125; ++c) {
    const int j = c * 64 + lane;
    int mval = (j < CN1) ? p0[j]
             : (j < CN1 + CN2) ? p1[j - CN1]
                               : p2[j - CN1 - CN2];
    unsigned long long bm = __ballot(mval > 0);
    if (lane == 0) {
      pkrow[(2 * c) * 16]     = (unsigned int)(bm & 0xffffffffull);
      pkrow[(2 * c + 1) * 16] = (unsigned int)(bm >> 32);
    }
  }
}

// ---------------- k_wh: block=128 (2 waves = 2 nodes), grid=4000, fp32 ------
__global__ void k_wh(const float* __restrict__ hv, const float* __restrict__ Wsv,
                     const float* __restrict__ ap,
                     float* __restrict__ Whf,    // [2][8000][64]
                     float* __restrict__ Wh1s,   // [2][8000] = (Wh·a1)*log2e
                     float* __restrict__ Wh2s) { // [2][8000] = (Wh·a2)*log2e
  const int t = threadIdx.x;
  const int o = t & 63;
  const int n = blockIdx.x * 2 + (t >> 6);
  const float* hrow = hv + n * INF_;
  const float* Ws0 = Wsv + o;
  const float* Ws1 = Wsv + INF_ * OUTF + o;
  float a0a = 0.f, a0b = 0.f, a1a = 0.f, a1b = 0.f;
#pragma unroll 8
  for (int f = 0; f < INF_; f += 2) {
    float h0 = hrow[f], h1 = hrow[f + 1];
    a0a += h0 * Ws0[f * OUTF];
    a0b += h1 * Ws0[(f + 1) * OUTF];
    a1a += h0 * Ws1[f * OUTF];
    a1b += h1 * Ws1[(f + 1) * OUTF];
  }
  float acc0 = a0a + a0b, acc1 = a1a + a1b;
  Whf[(0 * NTOT + n) * OUTF + o] = acc0;
  Whf[(1 * NTOT + n) * OUTF + o] = acc1;
  float s10 = wave_sum(acc0 * ap[o]);
  float s20 = wave_sum(acc0 * ap[OUTF + o]);
  float s11 = wave_sum(acc1 * ap[2 * OUTF + o]);
  float s21 = wave_sum(acc1 * ap[3 * OUTF + o]);
  if (o == 0) {
    Wh1s[n] = s10 * LOG2E;        Wh2s[n] = s20 * LOG2E;
    Wh1s[NTOT + n] = s11 * LOG2E; Wh2s[NTOT + n] = s21 * LOG2E;
  }
}

// ---------------- k_m2 -------------------------------------------------------
__global__ void k_m2(const float* __restrict__ Wh2s, float* __restrict__ M2s) {
  const int hd = blockIdx.x;
  float mx = -1e30f;
  for (int i = threadIdx.x; i < NTOT; i += 256)
    mx = fmaxf(mx, Wh2s[hd * NTOT + i]);
  for (int d = 32; d; d >>= 1) mx = fmaxf(mx, __shfl_xor(mx, d, 64));
  __shared__ float red[4];
  if ((threadIdx.x & 63) == 0) red[threadIdx.x >> 6] = mx;
  __syncthreads();
  if (threadIdx.x == 0)
    M2s[hd] = fmaxf(fmaxf(red[0], red[1]), fmaxf(red[2], red[3]));
}

// ---------------- k_bpack: Wh -> bf16 B-fragments ---------------------------
__global__ void k_bpack(const float* __restrict__ Whf, int4* __restrict__ WhB) {
  const int gid = blockIdx.x * 256 + threadIdx.x;  // 128000 total
  const int lane = gid & 63;
  const int c = (gid >> 6) & 3;
  const int t = (gid >> 8) % 250;
  const int hd = gid / 64000;
  const int jb = t * 32 + (lane >> 4) * 8;
  const int col = c * 16 + (lane & 15);
  const float* src = Whf + (hd * NTOT + jb) * OUTF + col;
  B16x8 out;
#pragma unroll
  for (int e2 = 0; e2 < 4; ++e2)
    out.u[e2] = pack2_bf16(src[(2 * e2) * OUTF], src[(2 * e2 + 1) * OUTF]);
  WhB[gid] = out.i4;
}

// ---------------- k_attn_mfma: grid=(250, njy), block=128 -------------------
// wave = 16 rows x BOTH heads; mask from packed bits (4 B/lane/iter).
__global__ __launch_bounds__(128, 2)
void k_attn_mfma(const unsigned int* __restrict__ packed,
                 const float* __restrict__ Wh1s, const float* __restrict__ Wh2s,
                 const float* __restrict__ M2s, const int4* __restrict__ WhB,
                 float* __restrict__ partAcc,   // [njy][2][8000][64]
                 float* __restrict__ partS)     // [njy][2][8000]
{
  const int widx = threadIdx.x >> 6;
  const int lane = threadIdx.x & 63;
  const int m = lane & 15;
  const int g = lane >> 4;
  const int kb = g * 8;
  const int rowblk = blockIdx.x * 2 + widx;      // 0..499
  const int i = rowblk * 16 + m;
  const int jy = blockIdx.y, njy = gridDim.y;
  const int t0 = (250 * jy) / njy, t1 = (250 * (jy + 1)) / njy;

  const unsigned int* pkb = packed + rowblk * 4000 + m;

  const float w1s0 = Wh1s[i],        w1s1 = Wh1s[NTOT + i];
  const float y0 = w1s0 + M2s[0],    y1 = w1s1 + M2s[1];
  const float ci0 = fmaxf(y0, ALPHA * y0), ci1 = fmaxf(y1, ALPHA * y1);
  const float a1c0 = w1s0 - ci0, b1c0 = ALPHA * w1s0 - ci0;
  const float a1c1 = w1s1 - ci1, b1c1 = ALPHA * w1s1 - ci1;
  const float* wh2_0 = Wh2s;
  const float* wh2_1 = Wh2s + NTOT;

  f32x4 a0_0 = {0.f,0.f,0.f,0.f}, a0_1 = a0_0, a0_2 = a0_0, a0_3 = a0_0;
  f32x4 a1_0 = a0_0, a1_1 = a0_0, a1_2 = a0_0, a1_3 = a0_0;
  float sp0 = 0.f, sp1 = 0.f;

  struct Frags { int4 f0[4], f1[4]; float4 w0a, w0b, w1a, w1b; };
  auto load_frags = [&](int t, Frags& F) {
    const int4* bp0 = WhB + t * 256 + lane;
    const int4* bp1 = WhB + (250 + t) * 256 + lane;
#pragma unroll
    for (int c = 0; c < 4; ++c) { F.f0[c] = bp0[c * 64]; F.f1[c] = bp1[c * 64]; }
    const float* w0 = wh2_0 + t * 32 + kb;
    const float* w1 = wh2_1 + t * 32 + kb;
    F.w0a = *(const float4*)w0; F.w0b = *(const float4*)(w0 + 4);
    F.w1a = *(const float4*)w1; F.w1b = *(const float4*)(w1 + 4);
  };

  auto compute = [&](unsigned int mw, const Frags& F) {
    const unsigned bits = (mw >> kb) & 0xffu;
    const float w0v[8] = {F.w0a.x, F.w0a.y, F.w0a.z, F.w0a.w, F.w0b.x, F.w0b.y, F.w0b.z, F.w0b.w};
    const float w1v[8] = {F.w1a.x, F.w1a.y, F.w1a.z, F.w1a.w, F.w1b.x, F.w1b.y, F.w1b.z, F.w1b.w};
    float q0[8], q1[8];
#pragma unroll
    for (int e = 0; e < 8; ++e) {
      bool on = ((bits >> e) & 1u) != 0u;
      float xa0 = a1c0 + w0v[e];
      float xb0 = fmaf(ALPHA, w0v[e], b1c0);
      float p0e = EXP2F(fmaxf(xa0, xb0));
      q0[e] = on ? p0e : 0.f;
      float xa1 = a1c1 + w1v[e];
      float xb1 = fmaf(ALPHA, w1v[e], b1c1);
      float p1e = EXP2F(fmaxf(xa1, xb1));
      q1[e] = on ? p1e : 0.f;
    }
    sp0 += ((q0[0] + q0[1]) + (q0[2] + q0[3])) + ((q0[4] + q0[5]) + (q0[6] + q0[7]));
    sp1 += ((q1[0] + q1[1]) + (q1[2] + q1[3])) + ((q1[4] + q1[5]) + (q1[6] + q1[7]));
    B16x8 af0, af1;
#pragma unroll
    for (int e2 = 0; e2 < 4; ++e2) {
      af0.u[e2] = pack2_bf16(q0[2 * e2], q0[2 * e2 + 1]);
      af1.u[e2] = pack2_bf16(q1[2 * e2], q1[2 * e2 + 1]);
    }
    B16x8 b;
    b.i4 = F.f0[0]; a0_0 = __builtin_amdgcn_mfma_f32_16x16x32_bf16(af0.s8, b.s8, a0_0, 0, 0, 0);
    b.i4 = F.f0[1]; a0_1 = __builtin_amdgcn_mfma_f32_16x16x32_bf16(af0.s8, b.s8, a0_1, 0, 0, 0);
    b.i4 = F.f0[2]; a0_2 = __builtin_amdgcn_mfma_f32_16x16x32_bf16(af0.s8, b.s8, a0_2, 0, 0, 0);
    b.i4 = F.f0[3]; a0_3 = __builtin_amdgcn_mfma_f32_16x16x32_bf16(af0.s8, b.s8, a0_3, 0, 0, 0);
    b.i4 = F.f1[0]; a1_0 = __builtin_amdgcn_mfma_f32_16x16x32_bf16(af1.s8, b.s8, a1_0, 0, 0, 0);
    b.i4 = F.f1[1]; a1_1 = __builtin_amdgcn_mfma_f32_16x16x32_bf16(af1.s8, b.s8, a1_1, 0, 0, 0);
    b.i4 = F.f1[2]; a1_2 = __builtin_amdgcn_mfma_f32_16x16x32_bf16(af1.s8, b.s8, a1_2, 0, 0, 0);
    b.i4 = F.f1[3]; a1_3 = __builtin_amdgcn_mfma_f32_16x16x32_bf16(af1.s8, b.s8, a1_3, 0, 0, 0);
  };

  // pipeline: mask word 2 ahead, frags 1 ahead (all L2/L3-resident)
  unsigned int mw0 = pkb[t0 * 16];
  unsigned int mw1 = pkb[min(t0 + 1, t1 - 1) * 16];
  Frags Fc, Fn;
  load_frags(t0, Fc);
  for (int t = t0; t < t1; ++t) {
    load_frags(min(t + 1, t1 - 1), Fn);
    unsigned int mw2 = pkb[min(t + 2, t1 - 1) * 16];
    compute(mw0, Fc);
    mw0 = mw1; mw1 = mw2;
    Fc = Fn;
  }

  // row sums: row m lives on lanes {m, m+16, m+32, m+48}
  sp0 += __shfl_xor(sp0, 16, 64); sp0 += __shfl_xor(sp0, 32, 64);
  sp1 += __shfl_xor(sp1, 16, 64); sp1 += __shfl_xor(sp1, 32, 64);
  const int base0 = (jy * 2 + 0) * NTOT + rowblk * 16;
  const int base1 = (jy * 2 + 1) * NTOT + rowblk * 16;
  if (lane < 16) {
    partS[base0 + lane] = sp0;
    partS[base1 + lane] = sp1;
  }

  // C layout: col = lane&15 (feature), row = g*4 + q (node)
  float* o0 = partAcc + base0 * OUTF;
  float* o1 = partAcc + base1 * OUTF;
#pragma unroll
  for (int q = 0; q < 4; ++q) {
    const int row = g * 4 + q;
    o0[row * OUTF +      m] = a0_0[q];
    o0[row * OUTF + 16 + m] = a0_1[q];
    o0[row * OUTF + 32 + m] = a0_2[q];
    o0[row * OUTF + 48 + m] = a0_3[q];
    o1[row * OUTF +      m] = a1_0[q];
    o1[row * OUTF + 16 + m] = a1_1[q];
    o1[row * OUTF + 32 + m] = a1_2[q];
    o1[row * OUTF + 48 + m] = a1_3[q];
  }
}

// ---------------- k_final: combine njy + /s + ELU + log_softmax + store -----
__global__ void k_final(const float* __restrict__ partAcc, const float* __restrict__ partS,
                        int njy, float* __restrict__ out) {
  const int wave = threadIdx.x >> 6, lane = threadIdx.x & 63;
  const int n = blockIdx.x * 4 + wave;
  float x[2];
#pragma unroll
  for (int hd = 0; hd < 2; ++hd) {
    float a = 0.f, s = 0.f;
    for (int jy = 0; jy < njy; ++jy) {
      a += partAcc[((jy * 2 + hd) * NTOT + n) * OUTF + lane];
      s += partS[(jy * 2 + hd) * NTOT + n];
    }
    float mid = a / s;
    x[hd] = mid > 0.f ? mid : (__expf(mid) - 1.f);   // ELU(alpha=1)
  }
  float mx = fmaxf(x[0], x[1]);
  for (int d = 32; d; d >>= 1) mx = fmaxf(mx, __shfl_xor(mx, d, 64));
  float se = __expf(x[0] - mx) + __expf(x[1] - mx);
  for (int d = 32; d; d >>= 1) se += __shfl_xor(se, d, 64);
  const float lse = mx + __logf(se);
  const int orow = (n >= CN1 + CN2) ? (n - CN1 - CN2) : (n + CN3);
  out[orow * 128 + lane]      = x[0] - lse;
  out[orow * 128 + 64 + lane] = x[1] - lse;
}

__global__ void k_sentinel(float* __restrict__ out, float v) {
  out[blockIdx.x * 256 + threadIdx.x] = v;
}

// ---------------------------------------------------------------------------
extern "C" void kernel_launch(void* const* d_in, const int* in_sizes, int n_in,
                              void* d_out, int out_size, void* d_ws, size_t ws_size,
                              hipStream_t stream) {
  float* outf = (float*)d_out;

  static const int EXP[12] = {1024000, 9000000, 6250000, 6250000, 7500000, 7500000,
                              6250000, 7500000, 7500000, 6250000, 16384, 256};
  bool exact = (n_in == 12);
  if (exact) for (int i = 0; i < 12; ++i) if (in_sizes[i] != EXP[i]) { exact = false; break; }

  // ws layout: Wh1s 64000 | Wh2s 64000 | M2s 256 | WhB 2,048,000 |
  //            packed 8,000,000 | partS njy*64,000 |
  //            Whf 4,096,000 / partAcc njy*4,096,000 (overlay)
  const size_t FIXED = 64000 + 64000 + 256 + 2048000 + 8000000;   // 10,176,256
  int njy = 0;
  for (int cand = 4; cand >= 1; cand >>= 1) {
    size_t need = FIXED + (size_t)cand * 64000 + (size_t)cand * 4096000;
    if (ws_size >= need) { njy = cand; break; }
  }
  if (!exact || njy == 0) {
    k_sentinel<<<dim3(4000), dim3(256), 0, stream>>>(outf, -148.0f);
    return;
  }

  const float* h  = (const float*)d_in[0];
  const int* A1  = (const int*)d_in[1];
  const int* A2  = (const int*)d_in[2];
  const int* A3  = (const int*)d_in[3];
  const int* A12 = (const int*)d_in[4];
  const int* A13 = (const int*)d_in[5];
  const int* A23 = (const int*)d_in[6];
  const int* A21 = (const int*)d_in[7];
  const int* A31 = (const int*)d_in[8];
  const int* A32 = (const int*)d_in[9];
  const float* Ws = (const float*)d_in[10];
  const float* ap = (const float*)d_in[11];

  char* w = (char*)d_ws;
  float*        Wh1s    = (float*)(w);
  float*        Wh2s    = (float*)(w + 64000);
  float*        M2s     = (float*)(w + 128000);
  int4*         WhB     = (int4*) (w + 128256);
  unsigned int* packed  = (unsigned int*)(w + 2176256);
  float*        partS   = (float*)(w + 10176256);
  float*        Whf     = (float*)(w + 10176256 + (size_t)njy * 64000);
  float*        partAcc = Whf;                    // overlay (Whf dead after k_bpack)

  k_pack     <<<dim3(2000),     dim3(256), 0, stream>>>(A1, A12, A13, A21, A2, A23, A31, A32, A3,
                                                        packed);
  k_wh       <<<dim3(4000),     dim3(128), 0, stream>>>(h, Ws, ap, Whf, Wh1s, Wh2s);
  k_m2       <<<dim3(2),        dim3(256), 0, stream>>>(Wh2s, M2s);
  k_bpack    <<<dim3(500),      dim3(256), 0, stream>>>(Whf, WhB);
  k_attn_mfma<<<dim3(250, njy), dim3(128), 0, stream>>>(packed, Wh1s, Wh2s, M2s, WhB,
                                                        partAcc, partS);
  k_final    <<<dim3(2000),     dim3(256), 0, stream>>>(partAcc, partS, njy, outf);
}

// Round 17
// 397.248 us; speedup vs baseline: 1.0644x; 1.0644x over previous
//
#include <hip/hip_runtime.h>
#include <hip/hip_bf16.h>

// ---------------------------------------------------------------------------
// ROUND 17: k_pack MLP fix. R16 counters: k_pack at 125us, 1.15 TB/s HBM,
// 81% occupancy, VALU 14% — classic 1-load-in-flight latency binding
// (load -> ballot forces vmcnt(0) -> store). Restructure: 5 blocks x 25
// HOISTED independent loads (6.4 KB in flight/wave) before the 25 ballots.
// 2048 waves x 6.4 KB = 13 MB in flight >> BW*latency (~2.4 MB) => k_pack
// becomes supply-bound. Everything else byte-identical to R16.
// ---------------------------------------------------------------------------

#define CN1 3000
#define CN2 2500
#define CN3 2500
#define NTOT 8000
#define INF_ 128
#define OUTF 64
#define LOG2E 1.44269504088896340736f
#define ALPHA 0.2f

typedef __attribute__((ext_vector_type(4))) float f32x4;
typedef __attribute__((ext_vector_type(8))) short short8;
union B16x8 { int4 i4; short8 s8; unsigned int u[4]; };

#if defined(__has_builtin)
#if __has_builtin(__builtin_amdgcn_exp2f)
#define EXP2F(x) __builtin_amdgcn_exp2f(x)
#endif
#endif
#ifndef EXP2F
#define EXP2F(x) exp2f(x)
#endif

__device__ inline float wave_sum(float v) {
  for (int d = 32; d; d >>= 1) v += __shfl_xor(v, d, 64);
  return v;
}

__device__ inline unsigned int pack2_bf16(float a, float b) {
  unsigned ua = __float_as_uint(a);
  ua = (ua + 0x7FFFu + ((ua >> 16) & 1u)) >> 16;
  unsigned ub = __float_as_uint(b);
  ub = (ub + 0x7FFFu + ((ub >> 16) & 1u)) & 0xFFFF0000u;
  return ub | ua;
}

// ---------------- k_pack: mask -> bits, 25 loads in flight ------------------
// wave = one row i; 5 blocks x (25 hoisted loads + 25 ballots + stores).
__global__ __launch_bounds__(256)
void k_pack(const int* __restrict__ A1,  const int* __restrict__ A12, const int* __restrict__ A13,
            const int* __restrict__ A21, const int* __restrict__ A2,  const int* __restrict__ A23,
            const int* __restrict__ A31, const int* __restrict__ A32, const int* __restrict__ A3,
            unsigned int* __restrict__ packed) {
  const int i = blockIdx.x * 4 + (threadIdx.x >> 6);
  const int lane = threadIdx.x & 63;
  const int *p0, *p1, *p2;
  if (i < CN1)            { p0 = A1  + i * CN1;          p1 = A12 + i * CN2;          p2 = A13 + i * CN3; }
  else if (i < CN1 + CN2) { int r = i - CN1;       p0 = A21 + r * CN1; p1 = A2  + r * CN2; p2 = A23 + r * CN3; }
  else                    { int r = i - CN1 - CN2; p0 = A31 + r * CN1; p1 = A32 + r * CN2; p2 = A3  + r * CN3; }
  unsigned int* pkrow = packed + (i >> 4) * 4000 + (i & 15);
  for (int cb = 0; cb < 5; ++cb) {
    int v[25];
#pragma unroll
    for (int u = 0; u < 25; ++u) {
      const int j = (cb * 25 + u) * 64 + lane;
      v[u] = (j < CN1) ? p0[j]
           : (j < CN1 + CN2) ? p1[j - CN1]
                             : p2[j - CN1 - CN2];
    }
#pragma unroll
    for (int u = 0; u < 25; ++u) {
      unsigned long long bm = __ballot(v[u] > 0);
      const int c = cb * 25 + u;
      if (lane == 0) {
        pkrow[(2 * c) * 16]     = (unsigned int)(bm & 0xffffffffull);
        pkrow[(2 * c + 1) * 16] = (unsigned int)(bm >> 32);
      }
    }
  }
}

// ---------------- k_wh: block=128 (2 waves = 2 nodes), grid=4000, fp32 ------
__global__ void k_wh(const float* __restrict__ hv, const float* __restrict__ Wsv,
                     const float* __restrict__ ap,
                     float* __restrict__ Whf,    // [2][8000][64]
                     float* __restrict__ Wh1s,   // [2][8000] = (Wh·a1)*log2e
                     float* __restrict__ Wh2s) { // [2][8000] = (Wh·a2)*log2e
  const int t = threadIdx.x;
  const int o = t & 63;
  const int n = blockIdx.x * 2 + (t >> 6);
  const float* hrow = hv + n * INF_;
  const float* Ws0 = Wsv + o;
  const float* Ws1 = Wsv + INF_ * OUTF + o;
  float a0a = 0.f, a0b = 0.f, a1a = 0.f, a1b = 0.f;
#pragma unroll 8
  for (int f = 0; f < INF_; f += 2) {
    float h0 = hrow[f], h1 = hrow[f + 1];
    a0a += h0 * Ws0[f * OUTF];
    a0b += h1 * Ws0[(f + 1) * OUTF];
    a1a += h0 * Ws1[f * OUTF];
    a1b += h1 * Ws1[(f + 1) * OUTF];
  }
  float acc0 = a0a + a0b, acc1 = a1a + a1b;
  Whf[(0 * NTOT + n) * OUTF + o] = acc0;
  Whf[(1 * NTOT + n) * OUTF + o] = acc1;
  float s10 = wave_sum(acc0 * ap[o]);
  float s20 = wave_sum(acc0 * ap[OUTF + o]);
  float s11 = wave_sum(acc1 * ap[2 * OUTF + o]);
  float s21 = wave_sum(acc1 * ap[3 * OUTF + o]);
  if (o == 0) {
    Wh1s[n] = s10 * LOG2E;        Wh2s[n] = s20 * LOG2E;
    Wh1s[NTOT + n] = s11 * LOG2E; Wh2s[NTOT + n] = s21 * LOG2E;
  }
}

// ---------------- k_m2 -------------------------------------------------------
__global__ void k_m2(const float* __restrict__ Wh2s, float* __restrict__ M2s) {
  const int hd = blockIdx.x;
  float mx = -1e30f;
  for (int i = threadIdx.x; i < NTOT; i += 256)
    mx = fmaxf(mx, Wh2s[hd * NTOT + i]);
  for (int d = 32; d; d >>= 1) mx = fmaxf(mx, __shfl_xor(mx, d, 64));
  __shared__ float red[4];
  if ((threadIdx.x & 63) == 0) red[threadIdx.x >> 6] = mx;
  __syncthreads();
  if (threadIdx.x == 0)
    M2s[hd] = fmaxf(fmaxf(red[0], red[1]), fmaxf(red[2], red[3]));
}

// ---------------- k_bpack: Wh -> bf16 B-fragments ---------------------------
__global__ void k_bpack(const float* __restrict__ Whf, int4* __restrict__ WhB) {
  const int gid = blockIdx.x * 256 + threadIdx.x;  // 128000 total
  const int lane = gid & 63;
  const int c = (gid >> 6) & 3;
  const int t = (gid >> 8) % 250;
  const int hd = gid / 64000;
  const int jb = t * 32 + (lane >> 4) * 8;
  const int col = c * 16 + (lane & 15);
  const float* src = Whf + (hd * NTOT + jb) * OUTF + col;
  B16x8 out;
#pragma unroll
  for (int e2 = 0; e2 < 4; ++e2)
    out.u[e2] = pack2_bf16(src[(2 * e2) * OUTF], src[(2 * e2 + 1) * OUTF]);
  WhB[gid] = out.i4;
}

// ---------------- k_attn_mfma: grid=(250, njy), block=128 -------------------
// wave = 16 rows x BOTH heads; mask from packed bits (4 B/lane/iter).
__global__ __launch_bounds__(128, 2)
void k_attn_mfma(const unsigned int* __restrict__ packed,
                 const float* __restrict__ Wh1s, const float* __restrict__ Wh2s,
                 const float* __restrict__ M2s, const int4* __restrict__ WhB,
                 float* __restrict__ partAcc,   // [njy][2][8000][64]
                 float* __restrict__ partS)     // [njy][2][8000]
{
  const int widx = threadIdx.x >> 6;
  const int lane = threadIdx.x & 63;
  const int m = lane & 15;
  const int g = lane >> 4;
  const int kb = g * 8;
  const int rowblk = blockIdx.x * 2 + widx;      // 0..499
  const int i = rowblk * 16 + m;
  const int jy = blockIdx.y, njy = gridDim.y;
  const int t0 = (250 * jy) / njy, t1 = (250 * (jy + 1)) / njy;

  const unsigned int* pkb = packed + rowblk * 4000 + m;

  const float w1s0 = Wh1s[i],        w1s1 = Wh1s[NTOT + i];
  const float y0 = w1s0 + M2s[0],    y1 = w1s1 + M2s[1];
  const float ci0 = fmaxf(y0, ALPHA * y0), ci1 = fmaxf(y1, ALPHA * y1);
  const float a1c0 = w1s0 - ci0, b1c0 = ALPHA * w1s0 - ci0;
  const float a1c1 = w1s1 - ci1, b1c1 = ALPHA * w1s1 - ci1;
  const float* wh2_0 = Wh2s;
  const float* wh2_1 = Wh2s + NTOT;

  f32x4 a0_0 = {0.f,0.f,0.f,0.f}, a0_1 = a0_0, a0_2 = a0_0, a0_3 = a0_0;
  f32x4 a1_0 = a0_0, a1_1 = a0_0, a1_2 = a0_0, a1_3 = a0_0;
  float sp0 = 0.f, sp1 = 0.f;

  struct Frags { int4 f0[4], f1[4]; float4 w0a, w0b, w1a, w1b; };
  auto load_frags = [&](int t, Frags& F) {
    const int4* bp0 = WhB + t * 256 + lane;
    const int4* bp1 = WhB + (250 + t) * 256 + lane;
#pragma unroll
    for (int c = 0; c < 4; ++c) { F.f0[c] = bp0[c * 64]; F.f1[c] = bp1[c * 64]; }
    const float* w0 = wh2_0 + t * 32 + kb;
    const float* w1 = wh2_1 + t * 32 + kb;
    F.w0a = *(const float4*)w0; F.w0b = *(const float4*)(w0 + 4);
    F.w1a = *(const float4*)w1; F.w1b = *(const float4*)(w1 + 4);
  };

  auto compute = [&](unsigned int mw, const Frags& F) {
    const unsigned bits = (mw >> kb) & 0xffu;
    const float w0v[8] = {F.w0a.x, F.w0a.y, F.w0a.z, F.w0a.w, F.w0b.x, F.w0b.y, F.w0b.z, F.w0b.w};
    const float w1v[8] = {F.w1a.x, F.w1a.y, F.w1a.z, F.w1a.w, F.w1b.x, F.w1b.y, F.w1b.z, F.w1b.w};
    float q0[8], q1[8];
#pragma unroll
    for (int e = 0; e < 8; ++e) {
      bool on = ((bits >> e) & 1u) != 0u;
      float xa0 = a1c0 + w0v[e];
      float xb0 = fmaf(ALPHA, w0v[e], b1c0);
      float p0e = EXP2F(fmaxf(xa0, xb0));
      q0[e] = on ? p0e : 0.f;
      float xa1 = a1c1 + w1v[e];
      float xb1 = fmaf(ALPHA, w1v[e], b1c1);
      float p1e = EXP2F(fmaxf(xa1, xb1));
      q1[e] = on ? p1e : 0.f;
    }
    sp0 += ((q0[0] + q0[1]) + (q0[2] + q0[3])) + ((q0[4] + q0[5]) + (q0[6] + q0[7]));
    sp1 += ((q1[0] + q1[1]) + (q1[2] + q1[3])) + ((q1[4] + q1[5]) + (q1[6] + q1[7]));
    B16x8 af0, af1;
#pragma unroll
    for (int e2 = 0; e2 < 4; ++e2) {
      af0.u[e2] = pack2_bf16(q0[2 * e2], q0[2 * e2 + 1]);
      af1.u[e2] = pack2_bf16(q1[2 * e2], q1[2 * e2 + 1]);
    }
    B16x8 b;
    b.i4 = F.f0[0]; a0_0 = __builtin_amdgcn_mfma_f32_16x16x32_bf16(af0.s8, b.s8, a0_0, 0, 0, 0);
    b.i4 = F.f0[1]; a0_1 = __builtin_amdgcn_mfma_f32_16x16x32_bf16(af0.s8, b.s8, a0_1, 0, 0, 0);
    b.i4 = F.f0[2]; a0_2 = __builtin_amdgcn_mfma_f32_16x16x32_bf16(af0.s8, b.s8, a0_2, 0, 0, 0);
    b.i4 = F.f0[3]; a0_3 = __builtin_amdgcn_mfma_f32_16x16x32_bf16(af0.s8, b.s8, a0_3, 0, 0, 0);
    b.i4 = F.f1[0]; a1_0 = __builtin_amdgcn_mfma_f32_16x16x32_bf16(af1.s8, b.s8, a1_0, 0, 0, 0);
    b.i4 = F.f1[1]; a1_1 = __builtin_amdgcn_mfma_f32_16x16x32_bf16(af1.s8, b.s8, a1_1, 0, 0, 0);
    b.i4 = F.f1[2]; a1_2 = __builtin_amdgcn_mfma_f32_16x16x32_bf16(af1.s8, b.s8, a1_2, 0, 0, 0);
    b.i4 = F.f1[3]; a1_3 = __builtin_amdgcn_mfma_f32_16x16x32_bf16(af1.s8, b.s8, a1_3, 0, 0, 0);
  };

  // pipeline: mask word 2 ahead, frags 1 ahead (all L2/L3-resident)
  unsigned int mw0 = pkb[t0 * 16];
  unsigned int mw1 = pkb[min(t0 + 1, t1 - 1) * 16];
  Frags Fc, Fn;
  load_frags(t0, Fc);
  for (int t = t0; t < t1; ++t) {
    load_frags(min(t + 1, t1 - 1), Fn);
    unsigned int mw2 = pkb[min(t + 2, t1 - 1) * 16];
    compute(mw0, Fc);
    mw0 = mw1; mw1 = mw2;
    Fc = Fn;
  }

  // row sums: row m lives on lanes {m, m+16, m+32, m+48}
  sp0 += __shfl_xor(sp0, 16, 64); sp0 += __shfl_xor(sp0, 32, 64);
  sp1 += __shfl_xor(sp1, 16, 64); sp1 += __shfl_xor(sp1, 32, 64);
  const int base0 = (jy * 2 + 0) * NTOT + rowblk * 16;
  const int base1 = (jy * 2 + 1) * NTOT + rowblk * 16;
  if (lane < 16) {
    partS[base0 + lane] = sp0;
    partS[base1 + lane] = sp1;
  }

  // C layout: col = lane&15 (feature), row = g*4 + q (node)
  float* o0 = partAcc + base0 * OUTF;
  float* o1 = partAcc + base1 * OUTF;
#pragma unroll
  for (int q = 0; q < 4; ++q) {
    const int row = g * 4 + q;
    o0[row * OUTF +      m] = a0_0[q];
    o0[row * OUTF + 16 + m] = a0_1[q];
    o0[row * OUTF + 32 + m] = a0_2[q];
    o0[row * OUTF + 48 + m] = a0_3[q];
    o1[row * OUTF +      m] = a1_0[q];
    o1[row * OUTF + 16 + m] = a1_1[q];
    o1[row * OUTF + 32 + m] = a1_2[q];
    o1[row * OUTF + 48 + m] = a1_3[q];
  }
}

// ---------------- k_final: combine njy + /s + ELU + log_softmax + store -----
__global__ void k_final(const float* __restrict__ partAcc, const float* __restrict__ partS,
                        int njy, float* __restrict__ out) {
  const int wave = threadIdx.x >> 6, lane = threadIdx.x & 63;
  const int n = blockIdx.x * 4 + wave;
  float x[2];
#pragma unroll
  for (int hd = 0; hd < 2; ++hd) {
    float a = 0.f, s = 0.f;
    for (int jy = 0; jy < njy; ++jy) {
      a += partAcc[((jy * 2 + hd) * NTOT + n) * OUTF + lane];
      s += partS[(jy * 2 + hd) * NTOT + n];
    }
    float mid = a / s;
    x[hd] = mid > 0.f ? mid : (__expf(mid) - 1.f);   // ELU(alpha=1)
  }
  float mx = fmaxf(x[0], x[1]);
  for (int d = 32; d; d >>= 1) mx = fmaxf(mx, __shfl_xor(mx, d, 64));
  float se = __expf(x[0] - mx) + __expf(x[1] - mx);
  for (int d = 32; d; d >>= 1) se += __shfl_xor(se, d, 64);
  const float lse = mx + __logf(se);
  const int orow = (n >= CN1 + CN2) ? (n - CN1 - CN2) : (n + CN3);
  out[orow * 128 + lane]      = x[0] - lse;
  out[orow * 128 + 64 + lane] = x[1] - lse;
}

__global__ void k_sentinel(float* __restrict__ out, float v) {
  out[blockIdx.x * 256 + threadIdx.x] = v;
}

// ---------------------------------------------------------------------------
extern "C" void kernel_launch(void* const* d_in, const int* in_sizes, int n_in,
                              void* d_out, int out_size, void* d_ws, size_t ws_size,
                              hipStream_t stream) {
  float* outf = (float*)d_out;

  static const int EXP[12] = {1024000, 9000000, 6250000, 6250000, 7500000, 7500000,
                              6250000, 7500000, 7500000, 6250000, 16384, 256};
  bool exact = (n_in == 12);
  if (exact) for (int i = 0; i < 12; ++i) if (in_sizes[i] != EXP[i]) { exact = false; break; }

  // ws layout: Wh1s 64000 | Wh2s 64000 | M2s 256 | WhB 2,048,000 |
  //            packed 8,000,000 | partS njy*64,000 |
  //            Whf 4,096,000 / partAcc njy*4,096,000 (overlay)
  const size_t FIXED = 64000 + 64000 + 256 + 2048000 + 8000000;   // 10,176,256
  int njy = 0;
  for (int cand = 4; cand >= 1; cand >>= 1) {
    size_t need = FIXED + (size_t)cand * 64000 + (size_t)cand * 4096000;
    if (ws_size >= need) { njy = cand; break; }
  }
  if (!exact || njy == 0) {
    k_sentinel<<<dim3(4000), dim3(256), 0, stream>>>(outf, -148.0f);
    return;
  }

  const float* h  = (const float*)d_in[0];
  const int* A1  = (const int*)d_in[1];
  const int* A2  = (const int*)d_in[2];
  const int* A3  = (const int*)d_in[3];
  const int* A12 = (const int*)d_in[4];
  const int* A13 = (const int*)d_in[5];
  const int* A23 = (const int*)d_in[6];
  const int* A21 = (const int*)d_in[7];
  const int* A31 = (const int*)d_in[8];
  const int* A32 = (const int*)d_in[9];
  const float* Ws = (const float*)d_in[10];
  const float* ap = (const float*)d_in[11];

  char* w = (char*)d_ws;
  float*        Wh1s    = (float*)(w);
  float*        Wh2s    = (float*)(w + 64000);
  float*        M2s     = (float*)(w + 128000);
  int4*         WhB     = (int4*) (w + 128256);
  unsigned int* packed  = (unsigned int*)(w + 2176256);
  float*        partS   = (float*)(w + 10176256);
  float*        Whf     = (float*)(w + 10176256 + (size_t)njy * 64000);
  float*        partAcc = Whf;                    // overlay (Whf dead after k_bpack)

  k_pack     <<<dim3(2000),     dim3(256), 0, stream>>>(A1, A12, A13, A21, A2, A23, A31, A32, A3,
                                                        packed);
  k_wh       <<<dim3(4000),     dim3(128), 0, stream>>>(h, Ws, ap, Whf, Wh1s, Wh2s);
  k_m2       <<<dim3(2),        dim3(256), 0, stream>>>(Wh2s, M2s);
  k_bpack    <<<dim3(500),      dim3(256), 0, stream>>>(Whf, WhB);
  k_attn_mfma<<<dim3(250, njy), dim3(128), 0, stream>>>(packed, Wh1s, Wh2s, M2s, WhB,
                                                        partAcc, partS);
  k_final    <<<dim3(2000),     dim3(256), 0, stream>>>(partAcc, partS, njy, outf);
}

// Round 18
// 363.422 us; speedup vs baseline: 1.1634x; 1.0931x over previous
//
#include <hip/hip_runtime.h>
#include <hip/hip_bf16.h>

// ---------------------------------------------------------------------------
// ROUND 18: k_attn occupancy + VALU diet. R17 counters: k_attn 100us,
// Occupancy 20% (njy=4 => 2000 waves = 2/SIMD, grid-limited), VALU 38%,
// MFMA 6%, memory idle => latency-bound. Changes (all k_attn):
//  (1) intra-block t-split: both waves share a rowblk, disjoint t-halves,
//      LDS combine (10KB) => 2x waves at CONSTANT workspace; njy tier to 8.
//  (2) row sums via ones-MFMA (S = P @ 1) — kills the 14-add chains.
//  (3) v_cvt_pk_bf16_f32 via __float22bfloat162_rn for the A-frag pack.
// ---------------------------------------------------------------------------

#define CN1 3000
#define CN2 2500
#define CN3 2500
#define NTOT 8000
#define INF_ 128
#define OUTF 64
#define LOG2E 1.44269504088896340736f
#define ALPHA 0.2f

typedef __attribute__((ext_vector_type(4))) float f32x4;
typedef __attribute__((ext_vector_type(8))) short short8;
union B16x8 { int4 i4; short8 s8; unsigned int u[4]; };

#if defined(__has_builtin)
#if __has_builtin(__builtin_amdgcn_exp2f)
#define EXP2F(x) __builtin_amdgcn_exp2f(x)
#endif
#endif
#ifndef EXP2F
#define EXP2F(x) exp2f(x)
#endif

__device__ inline float wave_sum(float v) {
  for (int d = 32; d; d >>= 1) v += __shfl_xor(v, d, 64);
  return v;
}

// packed RNE f32x2 -> bf16x2 (v_cvt_pk_bf16_f32 on gfx950 via hip header)
__device__ inline unsigned int pk2(float a, float b) {
  union { __hip_bfloat162 h; unsigned int u; } cv;
  cv.h = __float22bfloat162_rn(make_float2(a, b));
  return cv.u;
}

__device__ inline unsigned int pack2_bf16(float a, float b) {
  unsigned ua = __float_as_uint(a);
  ua = (ua + 0x7FFFu + ((ua >> 16) & 1u)) >> 16;
  unsigned ub = __float_as_uint(b);
  ub = (ub + 0x7FFFu + ((ub >> 16) & 1u)) & 0xFFFF0000u;
  return ub | ua;
}

// ---------------- k_pack: mask -> bits, 25 loads in flight ------------------
__global__ __launch_bounds__(256)
void k_pack(const int* __restrict__ A1,  const int* __restrict__ A12, const int* __restrict__ A13,
            const int* __restrict__ A21, const int* __restrict__ A2,  const int* __restrict__ A23,
            const int* __restrict__ A31, const int* __restrict__ A32, const int* __restrict__ A3,
            unsigned int* __restrict__ packed) {
  const int i = blockIdx.x * 4 + (threadIdx.x >> 6);
  const int lane = threadIdx.x & 63;
  const int *p0, *p1, *p2;
  if (i < CN1)            { p0 = A1  + i * CN1;          p1 = A12 + i * CN2;          p2 = A13 + i * CN3; }
  else if (i < CN1 + CN2) { int r = i - CN1;       p0 = A21 + r * CN1; p1 = A2  + r * CN2; p2 = A23 + r * CN3; }
  else                    { int r = i - CN1 - CN2; p0 = A31 + r * CN1; p1 = A32 + r * CN2; p2 = A3  + r * CN3; }
  unsigned int* pkrow = packed + (i >> 4) * 4000 + (i & 15);
  for (int cb = 0; cb < 5; ++cb) {
    int v[25];
#pragma unroll
    for (int u = 0; u < 25; ++u) {
      const int j = (cb * 25 + u) * 64 + lane;
      v[u] = (j < CN1) ? p0[j]
           : (j < CN1 + CN2) ? p1[j - CN1]
                             : p2[j - CN1 - CN2];
    }
#pragma unroll
    for (int u = 0; u < 25; ++u) {
      unsigned long long bm = __ballot(v[u] > 0);
      const int c = cb * 25 + u;
      if (lane == 0) {
        pkrow[(2 * c) * 16]     = (unsigned int)(bm & 0xffffffffull);
        pkrow[(2 * c + 1) * 16] = (unsigned int)(bm >> 32);
      }
    }
  }
}

// ---------------- k_wh: block=128 (2 waves = 2 nodes), grid=4000, fp32 ------
__global__ void k_wh(const float* __restrict__ hv, const float* __restrict__ Wsv,
                     const float* __restrict__ ap,
                     float* __restrict__ Whf,    // [2][8000][64]
                     float* __restrict__ Wh1s,   // [2][8000] = (Wh·a1)*log2e
                     float* __restrict__ Wh2s) { // [2][8000] = (Wh·a2)*log2e
  const int t = threadIdx.x;
  const int o = t & 63;
  const int n = blockIdx.x * 2 + (t >> 6);
  const float* hrow = hv + n * INF_;
  const float* Ws0 = Wsv + o;
  const float* Ws1 = Wsv + INF_ * OUTF + o;
  float a0a = 0.f, a0b = 0.f, a1a = 0.f, a1b = 0.f;
#pragma unroll 8
  for (int f = 0; f < INF_; f += 2) {
    float h0 = hrow[f], h1 = hrow[f + 1];
    a0a += h0 * Ws0[f * OUTF];
    a0b += h1 * Ws0[(f + 1) * OUTF];
    a1a += h0 * Ws1[f * OUTF];
    a1b += h1 * Ws1[(f + 1) * OUTF];
  }
  float acc0 = a0a + a0b, acc1 = a1a + a1b;
  Whf[(0 * NTOT + n) * OUTF + o] = acc0;
  Whf[(1 * NTOT + n) * OUTF + o] = acc1;
  float s10 = wave_sum(acc0 * ap[o]);
  float s20 = wave_sum(acc0 * ap[OUTF + o]);
  float s11 = wave_sum(acc1 * ap[2 * OUTF + o]);
  float s21 = wave_sum(acc1 * ap[3 * OUTF + o]);
  if (o == 0) {
    Wh1s[n] = s10 * LOG2E;        Wh2s[n] = s20 * LOG2E;
    Wh1s[NTOT + n] = s11 * LOG2E; Wh2s[NTOT + n] = s21 * LOG2E;
  }
}

// ---------------- k_m2 -------------------------------------------------------
__global__ void k_m2(const float* __restrict__ Wh2s, float* __restrict__ M2s) {
  const int hd = blockIdx.x;
  float mx = -1e30f;
  for (int i = threadIdx.x; i < NTOT; i += 256)
    mx = fmaxf(mx, Wh2s[hd * NTOT + i]);
  for (int d = 32; d; d >>= 1) mx = fmaxf(mx, __shfl_xor(mx, d, 64));
  __shared__ float red[4];
  if ((threadIdx.x & 63) == 0) red[threadIdx.x >> 6] = mx;
  __syncthreads();
  if (threadIdx.x == 0)
    M2s[hd] = fmaxf(fmaxf(red[0], red[1]), fmaxf(red[2], red[3]));
}

// ---------------- k_bpack: Wh -> bf16 B-fragments ---------------------------
__global__ void k_bpack(const float* __restrict__ Whf, int4* __restrict__ WhB) {
  const int gid = blockIdx.x * 256 + threadIdx.x;  // 128000 total
  const int lane = gid & 63;
  const int c = (gid >> 6) & 3;
  const int t = (gid >> 8) % 250;
  const int hd = gid / 64000;
  const int jb = t * 32 + (lane >> 4) * 8;
  const int col = c * 16 + (lane & 15);
  const float* src = Whf + (hd * NTOT + jb) * OUTF + col;
  B16x8 out;
#pragma unroll
  for (int e2 = 0; e2 < 4; ++e2)
    out.u[e2] = pack2_bf16(src[(2 * e2) * OUTF], src[(2 * e2 + 1) * OUTF]);
  WhB[gid] = out.i4;
}

// ---------------- k_attn_mfma: grid=(500, njy), block=128 -------------------
// Both waves share rowblk = blockIdx.x, split the t-range; LDS combine.
__global__ __launch_bounds__(128)
void k_attn_mfma(const unsigned int* __restrict__ packed,
                 const float* __restrict__ Wh1s, const float* __restrict__ Wh2s,
                 const float* __restrict__ M2s, const int4* __restrict__ WhB,
                 float* __restrict__ partAcc,   // [njy][2][8000][64]
                 float* __restrict__ partS)     // [njy][2][8000]
{
  const int widx = threadIdx.x >> 6;
  const int lane = threadIdx.x & 63;
  const int m = lane & 15;
  const int g = lane >> 4;
  const int kb = g * 8;
  const int rowblk = blockIdx.x;                 // 0..499
  const int i = rowblk * 16 + m;
  const int jy = blockIdx.y, njy = gridDim.y;
  const int s = jy * 2 + widx, ns = njy * 2;     // t-slice index
  const int t0 = (250 * s) / ns, t1 = (250 * (s + 1)) / ns;

  const unsigned int* pkb = packed + rowblk * 4000 + m;

  const float w1s0 = Wh1s[i],        w1s1 = Wh1s[NTOT + i];
  const float y0 = w1s0 + M2s[0],    y1 = w1s1 + M2s[1];
  const float ci0 = fmaxf(y0, ALPHA * y0), ci1 = fmaxf(y1, ALPHA * y1);
  const float a1c0 = w1s0 - ci0, b1c0 = ALPHA * w1s0 - ci0;
  const float a1c1 = w1s1 - ci1, b1c1 = ALPHA * w1s1 - ci1;
  const float* wh2_0 = Wh2s;
  const float* wh2_1 = Wh2s + NTOT;

  f32x4 a0_0 = {0.f,0.f,0.f,0.f}, a0_1 = a0_0, a0_2 = a0_0, a0_3 = a0_0;
  f32x4 a1_0 = a0_0, a1_1 = a0_0, a1_2 = a0_0, a1_3 = a0_0;
  f32x4 s0v = a0_0, s1v = a0_0;                  // ones-MFMA row sums

  B16x8 ones;                                     // bf16 1.0 x8
#pragma unroll
  for (int e2 = 0; e2 < 4; ++e2) ones.u[e2] = 0x3F803F80u;

  struct Frags { int4 f0[4], f1[4]; float4 w0a, w0b, w1a, w1b; };
  auto load_frags = [&](int t, Frags& F) {
    const int4* bp0 = WhB + t * 256 + lane;
    const int4* bp1 = WhB + (250 + t) * 256 + lane;
#pragma unroll
    for (int c = 0; c < 4; ++c) { F.f0[c] = bp0[c * 64]; F.f1[c] = bp1[c * 64]; }
    const float* w0 = wh2_0 + t * 32 + kb;
    const float* w1 = wh2_1 + t * 32 + kb;
    F.w0a = *(const float4*)w0; F.w0b = *(const float4*)(w0 + 4);
    F.w1a = *(const float4*)w1; F.w1b = *(const float4*)(w1 + 4);
  };

  auto compute = [&](unsigned int mw, const Frags& F) {
    const unsigned bits = (mw >> kb) & 0xffu;
    const float w0v[8] = {F.w0a.x, F.w0a.y, F.w0a.z, F.w0a.w, F.w0b.x, F.w0b.y, F.w0b.z, F.w0b.w};
    const float w1v[8] = {F.w1a.x, F.w1a.y, F.w1a.z, F.w1a.w, F.w1b.x, F.w1b.y, F.w1b.z, F.w1b.w};
    float q0[8], q1[8];
#pragma unroll
    for (int e = 0; e < 8; ++e) {
      bool on = ((bits >> e) & 1u) != 0u;
      float xa0 = a1c0 + w0v[e];
      float xb0 = fmaf(ALPHA, w0v[e], b1c0);
      float p0e = EXP2F(fmaxf(xa0, xb0));
      q0[e] = on ? p0e : 0.f;
      float xa1 = a1c1 + w1v[e];
      float xb1 = fmaf(ALPHA, w1v[e], b1c1);
      float p1e = EXP2F(fmaxf(xa1, xb1));
      q1[e] = on ? p1e : 0.f;
    }
    B16x8 af0, af1;
#pragma unroll
    for (int e2 = 0; e2 < 4; ++e2) {
      af0.u[e2] = pk2(q0[2 * e2], q0[2 * e2 + 1]);
      af1.u[e2] = pk2(q1[2 * e2], q1[2 * e2 + 1]);
    }
    B16x8 b;
    b.i4 = F.f0[0]; a0_0 = __builtin_amdgcn_mfma_f32_16x16x32_bf16(af0.s8, b.s8, a0_0, 0, 0, 0);
    b.i4 = F.f0[1]; a0_1 = __builtin_amdgcn_mfma_f32_16x16x32_bf16(af0.s8, b.s8, a0_1, 0, 0, 0);
    b.i4 = F.f0[2]; a0_2 = __builtin_amdgcn_mfma_f32_16x16x32_bf16(af0.s8, b.s8, a0_2, 0, 0, 0);
    b.i4 = F.f0[3]; a0_3 = __builtin_amdgcn_mfma_f32_16x16x32_bf16(af0.s8, b.s8, a0_3, 0, 0, 0);
    s0v = __builtin_amdgcn_mfma_f32_16x16x32_bf16(af0.s8, ones.s8, s0v, 0, 0, 0);
    b.i4 = F.f1[0]; a1_0 = __builtin_amdgcn_mfma_f32_16x16x32_bf16(af1.s8, b.s8, a1_0, 0, 0, 0);
    b.i4 = F.f1[1]; a1_1 = __builtin_amdgcn_mfma_f32_16x16x32_bf16(af1.s8, b.s8, a1_1, 0, 0, 0);
    b.i4 = F.f1[2]; a1_2 = __builtin_amdgcn_mfma_f32_16x16x32_bf16(af1.s8, b.s8, a1_2, 0, 0, 0);
    b.i4 = F.f1[3]; a1_3 = __builtin_amdgcn_mfma_f32_16x16x32_bf16(af1.s8, b.s8, a1_3, 0, 0, 0);
    s1v = __builtin_amdgcn_mfma_f32_16x16x32_bf16(af1.s8, ones.s8, s1v, 0, 0, 0);
  };

  // pipeline: mask word 2 ahead, frags 1 ahead (all cache-resident)
  unsigned int mw0 = pkb[t0 * 16];
  unsigned int mw1 = pkb[min(t0 + 1, t1 - 1) * 16];
  Frags Fc, Fn;
  load_frags(t0, Fc);
  for (int t = t0; t < t1; ++t) {
    load_frags(min(t + 1, t1 - 1), Fn);
    unsigned int mw2 = pkb[min(t + 2, t1 - 1) * 16];
    compute(mw0, Fc);
    mw0 = mw1; mw1 = mw2;
    Fc = Fn;
  }

  // combine the two waves' partials via LDS (wave1 -> wave0)
  __shared__ f32x4 lds[10][64];
  if (widx == 1) {
    lds[0][lane] = a0_0; lds[1][lane] = a0_1; lds[2][lane] = a0_2; lds[3][lane] = a0_3;
    lds[4][lane] = a1_0; lds[5][lane] = a1_1; lds[6][lane] = a1_2; lds[7][lane] = a1_3;
    lds[8][lane] = s0v;  lds[9][lane] = s1v;
  }
  __syncthreads();
  if (widx == 0) {
    a0_0 += lds[0][lane]; a0_1 += lds[1][lane]; a0_2 += lds[2][lane]; a0_3 += lds[3][lane];
    a1_0 += lds[4][lane]; a1_1 += lds[5][lane]; a1_2 += lds[6][lane]; a1_3 += lds[7][lane];
    s0v  += lds[8][lane]; s1v  += lds[9][lane];

    const int base0 = (jy * 2 + 0) * NTOT + rowblk * 16;
    const int base1 = (jy * 2 + 1) * NTOT + rowblk * 16;
    // S: every column of the ones-MFMA D holds the row sum; rows g*4+q
    if (m == 0) {
#pragma unroll
      for (int q = 0; q < 4; ++q) {
        partS[base0 + g * 4 + q] = s0v[q];
        partS[base1 + g * 4 + q] = s1v[q];
      }
    }
    // C layout: col = lane&15 (feature), row = g*4 + q (node)
    float* o0 = partAcc + base0 * OUTF;
    float* o1 = partAcc + base1 * OUTF;
#pragma unroll
    for (int q = 0; q < 4; ++q) {
      const int row = g * 4 + q;
      o0[row * OUTF +      m] = a0_0[q];
      o0[row * OUTF + 16 + m] = a0_1[q];
      o0[row * OUTF + 32 + m] = a0_2[q];
      o0[row * OUTF + 48 + m] = a0_3[q];
      o1[row * OUTF +      m] = a1_0[q];
      o1[row * OUTF + 16 + m] = a1_1[q];
      o1[row * OUTF + 32 + m] = a1_2[q];
      o1[row * OUTF + 48 + m] = a1_3[q];
    }
  }
}

// ---------------- k_final: combine njy + /s + ELU + log_softmax + store -----
__global__ void k_final(const float* __restrict__ partAcc, const float* __restrict__ partS,
                        int njy, float* __restrict__ out) {
  const int wave = threadIdx.x >> 6, lane = threadIdx.x & 63;
  const int n = blockIdx.x * 4 + wave;
  float x[2];
#pragma unroll
  for (int hd = 0; hd < 2; ++hd) {
    float a = 0.f, s = 0.f;
    for (int jy = 0; jy < njy; ++jy) {
      a += partAcc[((jy * 2 + hd) * NTOT + n) * OUTF + lane];
      s += partS[(jy * 2 + hd) * NTOT + n];
    }
    float mid = a / s;
    x[hd] = mid > 0.f ? mid : (__expf(mid) - 1.f);   // ELU(alpha=1)
  }
  float mx = fmaxf(x[0], x[1]);
  for (int d = 32; d; d >>= 1) mx = fmaxf(mx, __shfl_xor(mx, d, 64));
  float se = __expf(x[0] - mx) + __expf(x[1] - mx);
  for (int d = 32; d; d >>= 1) se += __shfl_xor(se, d, 64);
  const float lse = mx + __logf(se);
  const int orow = (n >= CN1 + CN2) ? (n - CN1 - CN2) : (n + CN3);
  out[orow * 128 + lane]      = x[0] - lse;
  out[orow * 128 + 64 + lane] = x[1] - lse;
}

__global__ void k_sentinel(float* __restrict__ out, float v) {
  out[blockIdx.x * 256 + threadIdx.x] = v;
}

// ---------------------------------------------------------------------------
extern "C" void kernel_launch(void* const* d_in, const int* in_sizes, int n_in,
                              void* d_out, int out_size, void* d_ws, size_t ws_size,
                              hipStream_t stream) {
  float* outf = (float*)d_out;

  static const int EXP[12] = {1024000, 9000000, 6250000, 6250000, 7500000, 7500000,
                              6250000, 7500000, 7500000, 6250000, 16384, 256};
  bool exact = (n_in == 12);
  if (exact) for (int i = 0; i < 12; ++i) if (in_sizes[i] != EXP[i]) { exact = false; break; }

  // ws layout: Wh1s 64000 | Wh2s 64000 | M2s 256 | WhB 2,048,000 |
  //            packed 8,000,000 | partS njy*64,000 |
  //            Whf 4,096,000 / partAcc njy*4,096,000 (overlay)
  const size_t FIXED = 64000 + 64000 + 256 + 2048000 + 8000000;   // 10,176,256
  int njy = 0;
  for (int cand = 8; cand >= 1; cand >>= 1) {
    size_t need = FIXED + (size_t)cand * 64000 + (size_t)cand * 4096000;
    if (ws_size >= need) { njy = cand; break; }
  }
  if (!exact || njy == 0) {
    k_sentinel<<<dim3(4000), dim3(256), 0, stream>>>(outf, -148.0f);
    return;
  }

  const float* h  = (const float*)d_in[0];
  const int* A1  = (const int*)d_in[1];
  const int* A2  = (const int*)d_in[2];
  const int* A3  = (const int*)d_in[3];
  const int* A12 = (const int*)d_in[4];
  const int* A13 = (const int*)d_in[5];
  const int* A23 = (const int*)d_in[6];
  const int* A21 = (const int*)d_in[7];
  const int* A31 = (const int*)d_in[8];
  const int* A32 = (const int*)d_in[9];
  const float* Ws = (const float*)d_in[10];
  const float* ap = (const float*)d_in[11];

  char* w = (char*)d_ws;
  float*        Wh1s    = (float*)(w);
  float*        Wh2s    = (float*)(w + 64000);
  float*        M2s     = (float*)(w + 128000);
  int4*         WhB     = (int4*) (w + 128256);
  unsigned int* packed  = (unsigned int*)(w + 2176256);
  float*        partS   = (float*)(w + 10176256);
  float*        Whf     = (float*)(w + 10176256 + (size_t)njy * 64000);
  float*        partAcc = Whf;                    // overlay (Whf dead after k_bpack)

  k_pack     <<<dim3(2000),     dim3(256), 0, stream>>>(A1, A12, A13, A21, A2, A23, A31, A32, A3,
                                                        packed);
  k_wh       <<<dim3(4000),     dim3(128), 0, stream>>>(h, Ws, ap, Whf, Wh1s, Wh2s);
  k_m2       <<<dim3(2),        dim3(256), 0, stream>>>(Wh2s, M2s);
  k_bpack    <<<dim3(500),      dim3(256), 0, stream>>>(Whf, WhB);
  k_attn_mfma<<<dim3(500, njy), dim3(128), 0, stream>>>(packed, Wh1s, Wh2s, M2s, WhB,
                                                        partAcc, partS);
  k_final    <<<dim3(2000),     dim3(256), 0, stream>>>(partAcc, partS, njy, outf);
}